// Round 2
// baseline (221.040 us; speedup 1.0000x reference)
//
#include <hip/hip_runtime.h>
#include <math.h>

// MoE gate: gate = inp[16384,2048]f32 @ W[64,2048]^T + b[64]; top-2; softmax.
// d_out (float32): [tokens*2] indices-as-floats, then [tokens*2] scores.
//
// Round 4: fused single kernel, LDS-safe variant. Round-3 (BK=64, 139 KiB
// static LDS) died with a container failure; 139 KiB is above the 128 KiB
// verified-on-gfx950 precedent, so this version keeps the fusion but at
// BK=32 / 68 KiB LDS (well inside verified territory):
//  - 1024 threads/block = 4 wave-groups, each owning a K-split of 512
//    (identical accumulation order to the verified round-2 kernel).
//  - groups 1..3 dump partials into LDS (reusing dead staging memory),
//    group 0 reduces + bias + top-2 + softmax in-block. No d_ws, no
//    second dispatch, no 16.8MB partial round-trip.

#define KDIM 2048
#define NEXP 64
#define TM 64
#define BK 32
#define LDSS 68       // 64 + 4 pad: 272 B row stride (mult of 16 -> b128-aligned)
#define NGROUP 4
#define KSPLIT (KDIM / NGROUP)   // 512
#define NT (KSPLIT / BK)         // 16

__global__ __launch_bounds__(1024, 4) void gate_fused_kernel(
    const float* __restrict__ inp,
    const float* __restrict__ W,
    const float* __restrict__ bias,
    float* __restrict__ out,
    int tokens)
{
    // 4 groups x {A,W} x 32k x 68 x 4B = 69,632 B LDS (1 block/CU; grid == #CU)
    __shared__ float stage[NGROUP][2][BK][LDSS];

    const int tid = threadIdx.x;
    const int g   = tid >> 8;        // K-split wave-group 0..3 (wave-uniform)
    const int lt  = tid & 255;
    const int tx  = lt & 15;         // experts 4*tx..4*tx+3
    const int ty  = lt >> 4;         // tokens 4*ty..4*ty+3
    const int tokBase = blockIdx.x * TM;
    const int k0      = g * KSPLIT;

    float (*As)[LDSS] = stage[g][0];   // As[k][token]
    float (*Ws)[LDSS] = stage[g][1];   // Ws[k][expert]

    // staging map: 64 rows x 32 k f32 per tile; each thread: 4 float4 loads
    const int lrow = lt >> 3;           // 0..31
    const int lcol = (lt & 7) << 2;     // 0,4,...,28

    const float* aPtr0 = inp + (size_t)(tokBase + lrow)      * KDIM + k0 + lcol;
    const float* aPtr1 = inp + (size_t)(tokBase + lrow + 32) * KDIM + k0 + lcol;
    const float* wPtr0 = W   + (size_t)lrow        * KDIM + k0 + lcol;
    const float* wPtr1 = W   + (size_t)(lrow + 32) * KDIM + k0 + lcol;

    float4 aReg0 = *(const float4*)(aPtr0);
    float4 aReg1 = *(const float4*)(aPtr1);
    float4 wReg0 = *(const float4*)(wPtr0);
    float4 wReg1 = *(const float4*)(wPtr1);

    float acc[4][4];
    #pragma unroll
    for (int r = 0; r < 4; ++r)
        #pragma unroll
        for (int c = 0; c < 4; ++c) acc[r][c] = 0.0f;

    for (int kt = 0; kt < NT; ++kt) {
        __syncthreads();
        #pragma unroll
        for (int c = 0; c < 4; ++c) {
            As[lcol + c][lrow]      = ((const float*)&aReg0)[c];
            As[lcol + c][lrow + 32] = ((const float*)&aReg1)[c];
            Ws[lcol + c][lrow]      = ((const float*)&wReg0)[c];
            Ws[lcol + c][lrow + 32] = ((const float*)&wReg1)[c];
        }
        __syncthreads();
        if (kt + 1 < NT) {
            const int off = (kt + 1) * BK;
            aReg0 = *(const float4*)(aPtr0 + off);
            aReg1 = *(const float4*)(aPtr1 + off);
            wReg0 = *(const float4*)(wPtr0 + off);
            wReg1 = *(const float4*)(wPtr1 + off);
        }
        #pragma unroll 8
        for (int kk = 0; kk < BK; ++kk) {
            const float4 av = *(const float4*)&As[kk][ty << 2];
            const float4 wv = *(const float4*)&Ws[kk][tx << 2];
            const float a[4] = {av.x, av.y, av.z, av.w};
            const float w[4] = {wv.x, wv.y, wv.z, wv.w};
            #pragma unroll
            for (int r = 0; r < 4; ++r)
                #pragma unroll
                for (int c = 0; c < 4; ++c)
                    acc[r][c] = fmaf(a[r], w[c], acc[r][c]);
        }
    }

    // ---- in-block split-K reduction + top-2 + softmax ----
    __syncthreads();                       // all staging reads done
    float* part = &stage[0][0][0][0];      // reuse: 3 x [TM][LDSS] floats
                                           //   = 13,056 of 17,408 available

    if (g != 0) {
        const int pbase = ((g - 1) * TM + (ty << 2)) * LDSS + (tx << 2);
        #pragma unroll
        for (int r = 0; r < 4; ++r) {
            *(float4*)&part[pbase + r * LDSS] =
                make_float4(acc[r][0], acc[r][1], acc[r][2], acc[r][3]);
        }
    }
    __syncthreads();

    if (g == 0) {
        const float4 bv = *(const float4*)&bias[tx << 2];
        #pragma unroll
        for (int r = 0; r < 4; ++r) {
            // sum order: split0 (regs) + split1 + split2 + split3, then bias
            // (bitwise-identical to the verified round-2 reduce kernel)
            float4 v = make_float4(acc[r][0], acc[r][1], acc[r][2], acc[r][3]);
            #pragma unroll
            for (int s = 0; s < 3; ++s) {
                const float4 p = *(const float4*)
                    &part[(s * TM + (ty << 2) + r) * LDSS + (tx << 2)];
                v.x += p.x; v.y += p.y; v.z += p.z; v.w += p.w;
            }
            float gg[4] = { v.x + bv.x, v.y + bv.y, v.z + bv.z, v.w + bv.w };

            // local top-2 (ascending keeps lower index on ties, like lax.top_k)
            const int eBase = tx << 2;
            float v1 = gg[0]; int i1 = eBase;
            float v2 = -INFINITY; int i2 = -1;
            #pragma unroll
            for (int c = 1; c < 4; ++c) {
                const float vv = gg[c];
                const int   ii = eBase + c;
                if (vv > v1)      { v2 = v1; i2 = i1; v1 = vv; i1 = ii; }
                else if (vv > v2) { v2 = vv; i2 = ii; }
            }
            // 16-lane butterfly merge
            #pragma unroll
            for (int m = 1; m <= 8; m <<= 1) {
                const float ov1 = __shfl_xor(v1, m);
                const int   oi1 = __shfl_xor(i1, m);
                const float ov2 = __shfl_xor(v2, m);
                const int   oi2 = __shfl_xor(i2, m);
                const bool aw = (v1 > ov1) || (v1 == ov1 && i1 < oi1);
                const float nv1 = aw ? v1  : ov1;  const int ni1 = aw ? i1  : oi1;
                const float lv  = aw ? ov1 : v1;   const int li  = aw ? oi1 : i1;
                const float sv  = aw ? v2  : ov2;  const int si  = aw ? i2  : oi2;
                const bool sw = (sv > lv) || (sv == lv && si < li);
                v1 = nv1; i1 = ni1;
                v2 = sw ? sv : lv; i2 = sw ? si : li;
            }
            if (tx == 0) {
                const int token = tokBase + (ty << 2) + r;
                const float e2 = expf(v2 - v1);
                const float denom = 1.0f + e2;
                out[2 * token]     = (float)i1;
                out[2 * token + 1] = (float)i2;
                out[tokens * 2 + 2 * token]     = 1.0f / denom;
                out[tokens * 2 + 2 * token + 1] = e2 / denom;
            }
        }
    }
}

extern "C" void kernel_launch(void* const* d_in, const int* in_sizes, int n_in,
                              void* d_out, int out_size, void* d_ws, size_t ws_size,
                              hipStream_t stream) {
    const float* inp  = (const float*)d_in[0];
    const float* W    = (const float*)d_in[1];
    const float* bias = (const float*)d_in[2];
    float* out = (float*)d_out;
    (void)d_ws; (void)ws_size; (void)n_in; (void)out_size;

    const int tokens = in_sizes[0] / KDIM;   // 16384

    gate_fused_kernel<<<tokens / TM, 1024, 0, stream>>>(inp, W, bias, out, tokens);
}